// Round 2
// baseline (2084.360 us; speedup 1.0000x reference)
//
#include <hip/hip_runtime.h>
#include <math.h>

#define MDIM 4096
#define NDIM 4096
#define DDIM 256
#define N_ITER 30

// L[i,j] = log2 K = -12 - kappa*(xx_i + yy_j) + 2*kappa*dot  (xx=yy=1 after L2 norm)
// TWO_KAPPA = 10/ln2
#define TWO_KAPPA 14.426950408889634
#define CLCONST  (-12.0 - TWO_KAPPA)

// ---------- norms: xx[i], yy[j], Sxx ----------
__global__ void norms_kernel(const float* __restrict__ x, const float* __restrict__ y,
                             float* __restrict__ xx, float* __restrict__ yy,
                             float* __restrict__ Sxx) {
  int wid = threadIdx.x >> 6, lane = threadIdx.x & 63;
  int row = blockIdx.x * 4 + wid;
  const float* src = (row < MDIM) ? x : y;
  int r = (row < MDIM) ? row : row - MDIM;
  const float4* p = (const float4*)(src + (size_t)r * DDIM);
  float4 v = p[lane];
  float s = v.x*v.x + v.y*v.y + v.z*v.z + v.w*v.w;
  #pragma unroll
  for (int off = 32; off; off >>= 1) s += __shfl_down(s, off);
  if (lane == 0) {
    if (row < MDIM) { xx[r] = s; atomicAdd(Sxx, s); }
    else            { yy[r] = s; }
  }
}

// ---------- sx[k] = sum_i x[i,k] ----------
__global__ void sx_kernel(const float* __restrict__ x, float* __restrict__ sx) {
  int tx = threadIdx.x;
  int r0 = blockIdx.x * 16;
  float s = 0.f;
  #pragma unroll
  for (int r = 0; r < 16; ++r) s += x[(size_t)(r0 + r) * DDIM + tx];
  atomicAdd(&sx[tx], s);
}

// ---------- colM[j] = Sxx + MDIM*yy[j] - 2*dot(sx, y_j) ----------
__global__ void colM_kernel(const float* __restrict__ y, const float* __restrict__ sx,
                            const float* __restrict__ yy, const float* __restrict__ Sxx,
                            float* __restrict__ colM) {
  int wid = threadIdx.x >> 6, lane = threadIdx.x & 63;
  int j = blockIdx.x * 4 + wid;
  const float4* py = (const float4*)(y + (size_t)j * DDIM);
  const float4* ps = (const float4*)sx;
  float4 a = py[lane], b = ps[lane];
  float s = a.x*b.x + a.y*b.y + a.z*b.z + a.w*b.w;
  #pragma unroll
  for (int off = 32; off; off >>= 1) s += __shfl_down(s, off);
  if (lane == 0) colM[j] = *Sxx + (float)MDIM * yy[j] - 2.f * s;
}

// ---------- GEMM: D16[i,j] = round(dot(x_i,y_j) * 65536), plus maxdot ----------
#define BMT 128
#define BKT 32
#define APAD 132   // 132*4B = 528B row stride, 16B aligned
__global__ __launch_bounds__(256)
void gemm_d_kernel(const float* __restrict__ x, const float* __restrict__ y,
                   short* __restrict__ D16, float* __restrict__ maxdot) {
  __shared__ float As[BKT][APAD];
  __shared__ float Bs[BKT][APAD];
  int tid = threadIdx.x;
  int bm = blockIdx.x & 31, bn = blockIdx.x >> 5;
  int tx = tid & 15, ty = tid >> 4;
  float acc[8][8] = {};
  for (int k0 = 0; k0 < DDIM; k0 += BKT) {
    #pragma unroll
    for (int q = 0; q < 4; ++q) {
      int li = tid + 256 * q;
      int row = li >> 3, ks = (li & 7) * 4;
      float4 v = *(const float4*)(x + (size_t)(bm * BMT + row) * DDIM + k0 + ks);
      As[ks+0][row] = v.x; As[ks+1][row] = v.y; As[ks+2][row] = v.z; As[ks+3][row] = v.w;
    }
    #pragma unroll
    for (int q = 0; q < 4; ++q) {
      int li = tid + 256 * q;
      int row = li >> 3, ks = (li & 7) * 4;
      float4 v = *(const float4*)(y + (size_t)(bn * BMT + row) * DDIM + k0 + ks);
      Bs[ks+0][row] = v.x; Bs[ks+1][row] = v.y; Bs[ks+2][row] = v.z; Bs[ks+3][row] = v.w;
    }
    __syncthreads();
    #pragma unroll
    for (int kk = 0; kk < BKT; ++kk) {
      float a[8], b[8];
      float4 a0 = *(const float4*)&As[kk][ty*8];
      float4 a1 = *(const float4*)&As[kk][ty*8+4];
      a[0]=a0.x; a[1]=a0.y; a[2]=a0.z; a[3]=a0.w; a[4]=a1.x; a[5]=a1.y; a[6]=a1.z; a[7]=a1.w;
      #pragma unroll
      for (int cg = 0; cg < 4; ++cg) {
        float2 bv = *(const float2*)&Bs[kk][2*tx + 32*cg];
        b[2*cg] = bv.x; b[2*cg+1] = bv.y;
      }
      #pragma unroll
      for (int r = 0; r < 8; ++r)
        #pragma unroll
        for (int c = 0; c < 8; ++c) acc[r][c] = fmaf(a[r], b[c], acc[r][c]);
    }
    __syncthreads();
  }
  // epilogue: pack int16 pairs + block max dot
  float tmax = -1.f;
  #pragma unroll
  for (int r = 0; r < 8; ++r) {
    int row = bm*BMT + ty*8 + r;
    #pragma unroll
    for (int cg = 0; cg < 4; ++cg) {
      float d0 = acc[r][2*cg], d1 = acc[r][2*cg+1];
      tmax = fmaxf(tmax, fmaxf(d0, d1));
      int lo = __float2int_rn(fminf(fmaxf(d0 * 65536.f, -32767.f), 32767.f));
      int hi = __float2int_rn(fminf(fmaxf(d1 * 65536.f, -32767.f), 32767.f));
      int iv = (lo & 0xFFFF) | (hi << 16);
      int col = bn*BMT + 2*tx + 32*cg;
      *(int*)(D16 + (size_t)row * NDIM + col) = iv;
    }
  }
  __shared__ float sm[4];
  #pragma unroll
  for (int off = 32; off; off >>= 1) tmax = fmaxf(tmax, __shfl_down(tmax, off));
  int lane = tid & 63, wid = tid >> 6;
  if (lane == 0) sm[wid] = tmax;
  __syncthreads();
  if (tid == 0) {
    float m = fmaxf(fmaxf(sm[0], sm[1]), fmaxf(sm[2], sm[3]));
    atomicMax((int*)maxdot, __float_as_int(fmaxf(m, 0.f)));  // positives: int max == float max
  }
}

// ---------- iteration kernel ----------
// G_t = exp2(t*L + phi_i + psi_j).  Computes:
//   psi_t (prologue, from psi_{t-1}, ctil_{t-1}),  Sr/Sc from exact maxes,
//   row sums -> phi_{t+1},  col partial sums -> ctil_t (atomics).
// MODE: 0 = first (t=1, phi=psi=-6 const), 1 = mid, 2 = last (col sums only)
#define IR 16   // rows per block;  grid = 256 blocks, 1024 threads
template<int MODE>
__global__ __launch_bounds__(1024)
void iter_kernel(const short* __restrict__ D16,
                 const float* __restrict__ phi_in, float* __restrict__ phi_out,
                 const float* __restrict__ psi_in, float* __restrict__ psi_out,
                 const float* __restrict__ ct_in,  float* __restrict__ ct_out,
                 const float* __restrict__ maxdot, float* __restrict__ scalars,
                 int t, float sD, float tCL, float s2k) {
  __shared__ float rp[IR][17];
  __shared__ float redm[32];
  int tid = threadIdx.x;
  int lane = tid & 63, wid = tid >> 6;   // 16 waves
  int row0 = blockIdx.x * IR;
  int j0 = tid * 4;

  float tLmax = tCL + s2k * maxdot[0];

  // ---- prologue: psi_t for my 4 cols; block maxes of psi_t and phi_t ----
  float psi[4];
  float pmax, fmax_;
  if constexpr (MODE == 0) {
    psi[0] = psi[1] = psi[2] = psi[3] = -6.f;
    pmax = -6.f; fmax_ = -6.f;
  } else {
    float Sc_prev = scalars[2*(t-1)+1];
    float4 cv = *(const float4*)(ct_in + j0);
    float4 pv = *(const float4*)(psi_in + j0);
    psi[0] = 0.5f*(pv.x - Sc_prev - log2f(fmaxf(cv.x, 1e-30f)));
    psi[1] = 0.5f*(pv.y - Sc_prev - log2f(fmaxf(cv.y, 1e-30f)));
    psi[2] = 0.5f*(pv.z - Sc_prev - log2f(fmaxf(cv.z, 1e-30f)));
    psi[3] = 0.5f*(pv.w - Sc_prev - log2f(fmaxf(cv.w, 1e-30f)));
    pmax = fmaxf(fmaxf(psi[0], psi[1]), fmaxf(psi[2], psi[3]));
    float4 fv = *(const float4*)(phi_in + j0);
    fmax_ = fmaxf(fmaxf(fv.x, fv.y), fmaxf(fv.z, fv.w));
  }
  // block-wide max reduce (both at once)
  #pragma unroll
  for (int off = 32; off; off >>= 1) {
    pmax  = fmaxf(pmax,  __shfl_down(pmax, off));
    fmax_ = fmaxf(fmax_, __shfl_down(fmax_, off));
  }
  if (lane == 0) { redm[wid] = pmax; redm[16 + wid] = fmax_; }
  __syncthreads();
  float psimax = redm[0], phimax = redm[16];
  #pragma unroll
  for (int w = 1; w < 16; ++w) {
    psimax = fmaxf(psimax, redm[w]);
    phimax = fmaxf(phimax, redm[16 + w]);
  }
  float Sr = tLmax + psimax - 100.f;
  float Sc = tLmax + phimax - 100.f;
  if (blockIdx.x == 0) {
    *(float4*)(psi_out + j0) = make_float4(psi[0], psi[1], psi[2], psi[3]);
    if (tid == 0) { scalars[2*t] = Sr; scalars[2*t+1] = Sc; }
  }
  float W = tCL - Sr;
  float Psi0 = psi[0] + W, Psi1 = psi[1] + W, Psi2 = psi[2] + W, Psi3 = psi[3] + W;
  float Wc = tCL - Sc;

  // ---- main loop over rows ----
  float cacc0 = 0.f, cacc1 = 0.f, cacc2 = 0.f, cacc3 = 0.f;
  for (int r = 0; r < IR; ++r) {
    int row = row0 + r;
    float phi_row = (MODE == 0) ? -6.f : phi_in[row];
    float Crow = Wc + phi_row;
    int2 dv = *(const int2*)(D16 + (size_t)row * NDIM + j0);
    float d0 = (float)((short)(dv.x & 0xFFFF));
    float d1 = (float)(dv.x >> 16);
    float d2 = (float)((short)(dv.y & 0xFFFF));
    float d3 = (float)(dv.y >> 16);
    cacc0 += exp2f(fmaf(d0, sD, Crow));
    cacc1 += exp2f(fmaf(d1, sD, Crow));
    cacc2 += exp2f(fmaf(d2, sD, Crow));
    cacc3 += exp2f(fmaf(d3, sD, Crow));
    if constexpr (MODE != 2) {
      float racc = exp2f(fmaf(d0, sD, Psi0)) + exp2f(fmaf(d1, sD, Psi1))
                 + exp2f(fmaf(d2, sD, Psi2)) + exp2f(fmaf(d3, sD, Psi3));
      #pragma unroll
      for (int off = 32; off; off >>= 1) racc += __shfl_down(racc, off);
      if (lane == 0) rp[r][wid] = racc;
    }
  }
  if constexpr (MODE != 2) {
    __syncthreads();
    if (tid < IR) {
      float s = 0.f;
      #pragma unroll
      for (int w = 0; w < 16; ++w) s += rp[tid][w];
      int row = row0 + tid;
      float phi_row = (MODE == 0) ? -6.f : phi_in[row];
      phi_out[row] = 0.5f * (phi_row - Sr - log2f(fmaxf(s, 1e-30f)));
    }
  }
  atomicAdd(ct_out + j0 + 0, cacc0);
  atomicAdd(ct_out + j0 + 1, cacc1);
  atomicAdd(ct_out + j0 + 2, cacc2);
  atomicAdd(ct_out + j0 + 3, cacc3);
}

// ---------- loss = sum_j colsum_j * colM_j / m^2 ----------
__global__ __launch_bounds__(1024)
void loss_kernel(const float* __restrict__ ct30, const float* __restrict__ psi30,
                 const float* __restrict__ scalars, const float* __restrict__ colM,
                 float* __restrict__ out) {
  __shared__ float sp[16];
  int tid = threadIdx.x, lane = tid & 63, wid = tid >> 6;
  float Sc30 = scalars[2*30+1];
  int j0 = tid * 4;
  float4 cv = *(const float4*)(ct30 + j0);
  float4 pv = *(const float4*)(psi30 + j0);
  float4 mv = *(const float4*)(colM + j0);
  float s = exp2f(log2f(fmaxf(cv.x, 1e-30f)) + pv.x + Sc30 + log2f(mv.x))
          + exp2f(log2f(fmaxf(cv.y, 1e-30f)) + pv.y + Sc30 + log2f(mv.y))
          + exp2f(log2f(fmaxf(cv.z, 1e-30f)) + pv.z + Sc30 + log2f(mv.z))
          + exp2f(log2f(fmaxf(cv.w, 1e-30f)) + pv.w + Sc30 + log2f(mv.w));
  #pragma unroll
  for (int off = 32; off; off >>= 1) s += __shfl_down(s, off);
  if (lane == 0) sp[wid] = s;
  __syncthreads();
  if (tid == 0) {
    float tot = 0.f;
    #pragma unroll
    for (int w = 0; w < 16; ++w) tot += sp[w];
    out[0] = tot * (1.f / ((float)MDIM * (float)MDIM));
  }
}

extern "C" void kernel_launch(void* const* d_in, const int* in_sizes, int n_in,
                              void* d_out, int out_size, void* d_ws, size_t ws_size,
                              hipStream_t stream) {
  const float* x = (const float*)d_in[0];
  const float* y = (const float*)d_in[1];
  float* out = (float*)d_out;

  char* ws = (char*)d_ws;
  size_t off = 0;
  auto alloc = [&](size_t bytes) -> void* {
    void* p = ws + off;
    off += (bytes + 255) & ~(size_t)255;
    return p;
  };
  short* D16  = (short*)alloc((size_t)MDIM * NDIM * 2);   // 32 MB
  float* xx   = (float*)alloc(MDIM * 4);
  float* yy   = (float*)alloc(NDIM * 4);
  float* sx   = (float*)alloc(DDIM * 4);
  float* colM = (float*)alloc(NDIM * 4);
  float* Sxx  = (float*)alloc(4);
  float* maxd = (float*)alloc(4);
  float* scalars = (float*)alloc(64 * 4);
  float* phib[2], *psib[2], *ctb[2];
  phib[0] = (float*)alloc(MDIM * 4); phib[1] = (float*)alloc(MDIM * 4);
  psib[0] = (float*)alloc(NDIM * 4); psib[1] = (float*)alloc(NDIM * 4);
  ctb[0]  = (float*)alloc(NDIM * 4); ctb[1]  = (float*)alloc(NDIM * 4);

  hipMemsetAsync(Sxx, 0, 4, stream);
  hipMemsetAsync(maxd, 0, 4, stream);
  hipMemsetAsync(sx, 0, DDIM * 4, stream);
  norms_kernel<<<2048, 256, 0, stream>>>(x, y, xx, yy, Sxx);
  sx_kernel<<<256, 256, 0, stream>>>(x, sx);
  colM_kernel<<<1024, 256, 0, stream>>>(y, sx, yy, Sxx, colM);
  gemm_d_kernel<<<1024, 256, 0, stream>>>(x, y, D16, maxd);

  for (int t = 1; t <= N_ITER; ++t) {
    float sD  = (float)((double)t * TWO_KAPPA / 65536.0);
    float tCL = (float)((double)t * CLCONST);
    float s2k = (float)((double)t * TWO_KAPPA);
    int wi = t & 1, ri = (t - 1) & 1;   // ct/psi write idx, read idx
    hipMemsetAsync(ctb[wi], 0, NDIM * 4, stream);
    if (t == 1) {
      iter_kernel<0><<<256, 1024, 0, stream>>>(D16,
          phib[1], phib[0], psib[0], psib[1], ctb[0], ctb[1],
          maxd, scalars, t, sD, tCL, s2k);
    } else if (t < N_ITER) {
      iter_kernel<1><<<256, 1024, 0, stream>>>(D16,
          phib[t & 1], phib[(t + 1) & 1], psib[ri], psib[wi], ctb[ri], ctb[wi],
          maxd, scalars, t, sD, tCL, s2k);
    } else {
      iter_kernel<2><<<256, 1024, 0, stream>>>(D16,
          phib[t & 1], phib[(t + 1) & 1], psib[ri], psib[wi], ctb[ri], ctb[wi],
          maxd, scalars, t, sD, tCL, s2k);
    }
  }
  loss_kernel<<<1, 1024, 0, stream>>>(ctb[0], psib[0], scalars, colM, out);
}

// Round 4
// 851.486 us; speedup vs baseline: 2.4479x; 2.4479x over previous
//
#include <hip/hip_runtime.h>
#include <math.h>

#define MDIM 4096
#define NDIM 4096
#define DDIM 256
#define N_ITER 30

#define TWO_KAPPA 14.426950408889634
#define CLCONST  (-12.0 - TWO_KAPPA)

// monotone float <-> uint encoding for atomicMax on possibly-negative floats
__device__ __forceinline__ unsigned encf(float f) {
  unsigned u = __float_as_uint(f);
  return (u & 0x80000000u) ? ~u : (u | 0x80000000u);
}
__device__ __forceinline__ float decf(unsigned u) {
  return __uint_as_float((u & 0x80000000u) ? (u ^ 0x80000000u) : ~u);
}

// ---------- norms: xx[i], yy[j], Sxx ----------
__global__ void norms_kernel(const float* __restrict__ x, const float* __restrict__ y,
                             float* __restrict__ xx, float* __restrict__ yy,
                             float* __restrict__ Sxx) {
  int wid = threadIdx.x >> 6, lane = threadIdx.x & 63;
  int row = blockIdx.x * 4 + wid;
  const float* src = (row < MDIM) ? x : y;
  int r = (row < MDIM) ? row : row - MDIM;
  const float4* p = (const float4*)(src + (size_t)r * DDIM);
  float4 v = p[lane];
  float s = v.x*v.x + v.y*v.y + v.z*v.z + v.w*v.w;
  #pragma unroll
  for (int off = 32; off; off >>= 1) s += __shfl_down(s, off);
  if (lane == 0) {
    if (row < MDIM) { xx[r] = s; atomicAdd(Sxx, s); }
    else            { yy[r] = s; }
  }
}

// ---------- sx[k] = sum_i x[i,k] ----------
__global__ void sx_kernel(const float* __restrict__ x, float* __restrict__ sx) {
  int tx = threadIdx.x;
  int r0 = blockIdx.x * 16;
  float s = 0.f;
  #pragma unroll
  for (int r = 0; r < 16; ++r) s += x[(size_t)(r0 + r) * DDIM + tx];
  atomicAdd(&sx[tx], s);
}

// ---------- colM[j] = Sxx + MDIM*yy[j] - 2*dot(sx, y_j) ----------
__global__ void colM_kernel(const float* __restrict__ y, const float* __restrict__ sx,
                            const float* __restrict__ yy, const float* __restrict__ Sxx,
                            float* __restrict__ colM) {
  int wid = threadIdx.x >> 6, lane = threadIdx.x & 63;
  int j = blockIdx.x * 4 + wid;
  const float4* py = (const float4*)(y + (size_t)j * DDIM);
  const float4* ps = (const float4*)sx;
  float4 a = py[lane], b = ps[lane];
  float s = a.x*b.x + a.y*b.y + a.z*b.z + a.w*b.w;
  #pragma unroll
  for (int off = 32; off; off >>= 1) s += __shfl_down(s, off);
  if (lane == 0) colM[j] = *Sxx + (float)MDIM * yy[j] - 2.f * s;
}

// ---------- GEMM: D16[i,j] = round(dot(x_i,y_j) * 65536), plus maxdot ----------
#define BMT 128
#define BKT 32
#define APAD 132
__global__ __launch_bounds__(256)
void gemm_d_kernel(const float* __restrict__ x, const float* __restrict__ y,
                   short* __restrict__ D16, float* __restrict__ maxdot) {
  __shared__ float As[BKT][APAD];
  __shared__ float Bs[BKT][APAD];
  int tid = threadIdx.x;
  int bm = blockIdx.x & 31, bn = blockIdx.x >> 5;
  int tx = tid & 15, ty = tid >> 4;
  float acc[8][8] = {};
  for (int k0 = 0; k0 < DDIM; k0 += BKT) {
    #pragma unroll
    for (int q = 0; q < 4; ++q) {
      int li = tid + 256 * q;
      int row = li >> 3, ks = (li & 7) * 4;
      float4 v = *(const float4*)(x + (size_t)(bm * BMT + row) * DDIM + k0 + ks);
      As[ks+0][row] = v.x; As[ks+1][row] = v.y; As[ks+2][row] = v.z; As[ks+3][row] = v.w;
    }
    #pragma unroll
    for (int q = 0; q < 4; ++q) {
      int li = tid + 256 * q;
      int row = li >> 3, ks = (li & 7) * 4;
      float4 v = *(const float4*)(y + (size_t)(bn * BMT + row) * DDIM + k0 + ks);
      Bs[ks+0][row] = v.x; Bs[ks+1][row] = v.y; Bs[ks+2][row] = v.z; Bs[ks+3][row] = v.w;
    }
    __syncthreads();
    #pragma unroll
    for (int kk = 0; kk < BKT; ++kk) {
      float a[8], b[8];
      float4 a0 = *(const float4*)&As[kk][ty*8];
      float4 a1 = *(const float4*)&As[kk][ty*8+4];
      a[0]=a0.x; a[1]=a0.y; a[2]=a0.z; a[3]=a0.w; a[4]=a1.x; a[5]=a1.y; a[6]=a1.z; a[7]=a1.w;
      #pragma unroll
      for (int cg = 0; cg < 4; ++cg) {
        float2 bv = *(const float2*)&Bs[kk][2*tx + 32*cg];
        b[2*cg] = bv.x; b[2*cg+1] = bv.y;
      }
      #pragma unroll
      for (int r = 0; r < 8; ++r)
        #pragma unroll
        for (int c = 0; c < 8; ++c) acc[r][c] = fmaf(a[r], b[c], acc[r][c]);
    }
    __syncthreads();
  }
  float tmax = -1.f;
  #pragma unroll
  for (int r = 0; r < 8; ++r) {
    int row = bm*BMT + ty*8 + r;
    #pragma unroll
    for (int cg = 0; cg < 4; ++cg) {
      float d0 = acc[r][2*cg], d1 = acc[r][2*cg+1];
      tmax = fmaxf(tmax, fmaxf(d0, d1));
      int lo = __float2int_rn(fminf(fmaxf(d0 * 65536.f, -32767.f), 32767.f));
      int hi = __float2int_rn(fminf(fmaxf(d1 * 65536.f, -32767.f), 32767.f));
      int iv = (lo & 0xFFFF) | (hi << 16);
      int col = bn*BMT + 2*tx + 32*cg;
      *(int*)(D16 + (size_t)row * NDIM + col) = iv;
    }
  }
  __shared__ float sm[4];
  #pragma unroll
  for (int off = 32; off; off >>= 1) tmax = fmaxf(tmax, __shfl_down(tmax, off));
  int lane = tid & 63, wid = tid >> 6;
  if (lane == 0) sm[wid] = tmax;
  __syncthreads();
  if (tid == 0) {
    float m = fmaxf(fmaxf(sm[0], sm[1]), fmaxf(sm[2], sm[3]));
    atomicMax((int*)maxdot, __float_as_int(fmaxf(m, 0.f)));
  }
}

// ---------- main iteration kernel (no global atomics on hot path) ----------
#define IR 16
template<int MODE>   // 0: t==1 (phi=psi=-6 const), 1: t>=2
__global__ __launch_bounds__(1024)
void iter_kernel(const short* __restrict__ D16,
                 const float* __restrict__ phi_in, float* __restrict__ phi_out,
                 const float* __restrict__ psi_in,
                 float* __restrict__ partial,
                 const float* __restrict__ maxdot,
                 const unsigned* __restrict__ psimaxU,
                 unsigned* __restrict__ phimaxU,
                 int t, float sD, float tCL, float s2k) {
  __shared__ float rp[IR][17];
  int tid = threadIdx.x;
  int lane = tid & 63, wid = tid >> 6;
  int row0 = blockIdx.x * IR;
  int j0 = tid * 4;

  float tLmax = fmaf(s2k, maxdot[0], tCL);
  float psimax, phimax, p0, p1, p2, p3;
  if constexpr (MODE == 0) {
    psimax = -6.f; phimax = -6.f;
    p0 = p1 = p2 = p3 = -6.f;
  } else {
    psimax = decf(psimaxU[t]);
    phimax = decf(phimaxU[t]);
    float4 pv = *(const float4*)(psi_in + j0);
    p0 = pv.x; p1 = pv.y; p2 = pv.z; p3 = pv.w;
  }
  float Sr = tLmax + psimax - 100.f;
  float Sc = tLmax + phimax - 100.f;
  float W  = tCL - Sr;
  float Wc = tCL - Sc;
  float P0 = p0 + W, P1 = p1 + W, P2 = p2 + W, P3 = p3 + W;

  float c0 = 0.f, c1 = 0.f, c2 = 0.f, c3 = 0.f;
  #pragma unroll 4
  for (int r = 0; r < IR; ++r) {
    int row = row0 + r;
    float phi_row = (MODE == 0) ? -6.f : phi_in[row];
    float Crow = Wc + phi_row;
    int2 dv = *(const int2*)(D16 + (size_t)row * NDIM + j0);
    float d0 = (float)((short)(dv.x & 0xFFFF));
    float d1 = (float)(dv.x >> 16);
    float d2 = (float)((short)(dv.y & 0xFFFF));
    float d3 = (float)(dv.y >> 16);
    c0 += exp2f(fmaf(d0, sD, Crow));
    c1 += exp2f(fmaf(d1, sD, Crow));
    c2 += exp2f(fmaf(d2, sD, Crow));
    c3 += exp2f(fmaf(d3, sD, Crow));
    float racc = exp2f(fmaf(d0, sD, P0)) + exp2f(fmaf(d1, sD, P1))
               + exp2f(fmaf(d2, sD, P2)) + exp2f(fmaf(d3, sD, P3));
    #pragma unroll
    for (int off = 32; off; off >>= 1) racc += __shfl_down(racc, off);
    if (lane == 0) rp[r][wid] = racc;
  }
  __syncthreads();
  if (tid < IR) {
    float s = 0.f;
    #pragma unroll
    for (int w = 0; w < 16; ++w) s += rp[tid][w];
    int row = row0 + tid;
    float phi_row = (MODE == 0) ? -6.f : phi_in[row];
    float pn = 0.5f * (phi_row - Sr - log2f(fmaxf(s, 1e-30f)));
    phi_out[row] = pn;
    #pragma unroll
    for (int off = 8; off; off >>= 1) pn = fmaxf(pn, __shfl_down(pn, off));
    if (tid == 0) atomicMax(&phimaxU[t + 1], encf(pn));
  }
  *(float4*)(partial + (size_t)blockIdx.x * NDIM + j0) = make_float4(c0, c1, c2, c3);
}

// ---------- finish: reduce partials -> ct; psi_out = 0.5(psi_in - Sc_{t-1} - log2 ct) ----------
template<int FIRST>   // FIRST=1 when t==2 (psi_1 = -6, phimax_1 = -6 constants)
__global__ __launch_bounds__(1024)
void finish_kernel(const float* __restrict__ partial,
                   const float* __restrict__ psi_in, float* __restrict__ psi_out,
                   float* __restrict__ ct,
                   const float* __restrict__ maxdot,
                   unsigned* __restrict__ psimaxU,
                   const unsigned* __restrict__ phimaxU,
                   int t, float prevCL, float prev_s2k) {
  __shared__ float red[8][132];
  __shared__ float sm[2];
  int tid = threadIdx.x;
  int jloc = tid & 127, c = tid >> 7;
  int j = blockIdx.x * 128 + jloc;
  float s = 0.f;
  #pragma unroll
  for (int k = 0; k < 32; ++k)
    s += partial[(size_t)(c * 32 + k) * NDIM + j];
  red[c][jloc] = s;
  __syncthreads();
  if (tid < 128) {
    float tot = red[0][jloc];
    #pragma unroll
    for (int cc = 1; cc < 8; ++cc) tot += red[cc][jloc];
    float tLmax_prev = fmaf(prev_s2k, maxdot[0], prevCL);
    float phimax_prev = FIRST ? -6.f : decf(phimaxU[t - 1]);
    float Sc_prev = tLmax_prev + phimax_prev - 100.f;
    float psi_prev = FIRST ? -6.f : psi_in[j];
    float pn = 0.5f * (psi_prev - Sc_prev - log2f(fmaxf(tot, 1e-30f)));
    psi_out[j] = pn;
    ct[j] = tot;
    int lane = tid & 63;
    #pragma unroll
    for (int off = 32; off; off >>= 1) pn = fmaxf(pn, __shfl_down(pn, off));
    if (lane == 0) sm[tid >> 6] = pn;
  }
  __syncthreads();
  if (tid == 0) atomicMax(&psimaxU[t], encf(fmaxf(sm[0], sm[1])));
}

// ---------- loss: colsum_j(G30) = 2^{psi30_j} * 2^{Sc30} * ct_j ----------
__global__ __launch_bounds__(1024)
void loss_kernel(const float* __restrict__ ct, const float* __restrict__ psi30,
                 const float* __restrict__ colM,
                 const float* __restrict__ maxdot, const unsigned* __restrict__ phimaxU,
                 float* __restrict__ out, float lastCL, float last_s2k) {
  __shared__ float sp[16];
  int tid = threadIdx.x, lane = tid & 63, wid = tid >> 6;
  int j0 = tid * 4;
  float tLmax = fmaf(last_s2k, maxdot[0], lastCL);
  float Sc30 = tLmax + decf(phimaxU[N_ITER]) - 100.f;
  float4 cv = *(const float4*)(ct + j0);
  float4 pv = *(const float4*)(psi30 + j0);
  float4 mv = *(const float4*)(colM + j0);
  float s = exp2f(log2f(fmaxf(cv.x, 1e-30f)) + pv.x + Sc30 + log2f(mv.x))
          + exp2f(log2f(fmaxf(cv.y, 1e-30f)) + pv.y + Sc30 + log2f(mv.y))
          + exp2f(log2f(fmaxf(cv.z, 1e-30f)) + pv.z + Sc30 + log2f(mv.z))
          + exp2f(log2f(fmaxf(cv.w, 1e-30f)) + pv.w + Sc30 + log2f(mv.w));
  #pragma unroll
  for (int off = 32; off; off >>= 1) s += __shfl_down(s, off);
  if (lane == 0) sp[wid] = s;
  __syncthreads();
  if (tid == 0) {
    float tot = 0.f;
    #pragma unroll
    for (int w = 0; w < 16; ++w) tot += sp[w];
    out[0] = tot * (1.f / ((float)MDIM * (float)MDIM));
  }
}

extern "C" void kernel_launch(void* const* d_in, const int* in_sizes, int n_in,
                              void* d_out, int out_size, void* d_ws, size_t ws_size,
                              hipStream_t stream) {
  const float* x = (const float*)d_in[0];
  const float* y = (const float*)d_in[1];
  float* out = (float*)d_out;

  char* ws = (char*)d_ws;
  size_t off = 0;
  auto alloc = [&](size_t bytes) -> void* {
    void* p = ws + off;
    off += (bytes + 255) & ~(size_t)255;
    return p;
  };
  short*    D16     = (short*)alloc((size_t)MDIM * NDIM * 2);      // 32 MB
  float*    partial = (float*)alloc((size_t)256 * NDIM * 4);       // 4 MB
  float*    xx      = (float*)alloc(MDIM * 4);
  float*    yy      = (float*)alloc(NDIM * 4);
  float*    sx      = (float*)alloc(DDIM * 4);
  float*    colM    = (float*)alloc(NDIM * 4);
  float*    Sxx     = (float*)alloc(4);
  float*    maxd    = (float*)alloc(4);
  unsigned* psimaxU = (unsigned*)alloc(64 * 4);
  unsigned* phimaxU = (unsigned*)alloc(64 * 4);
  float*    psi     = (float*)alloc(NDIM * 4);
  float*    psidmy  = (float*)alloc(NDIM * 4);
  float*    ct      = (float*)alloc(NDIM * 4);
  float*    phib[2];
  phib[0] = (float*)alloc(MDIM * 4); phib[1] = (float*)alloc(MDIM * 4);

  hipMemsetAsync(Sxx, 0, 4, stream);
  hipMemsetAsync(maxd, 0, 4, stream);
  hipMemsetAsync(sx, 0, DDIM * 4, stream);
  hipMemsetAsync(psimaxU, 0, 64 * 4, stream);
  hipMemsetAsync(phimaxU, 0, 64 * 4, stream);

  norms_kernel<<<2048, 256, 0, stream>>>(x, y, xx, yy, Sxx);
  sx_kernel<<<256, 256, 0, stream>>>(x, sx);
  colM_kernel<<<1024, 256, 0, stream>>>(y, sx, yy, Sxx, colM);
  gemm_d_kernel<<<1024, 256, 0, stream>>>(x, y, D16, maxd);

  // t = 1 (phi = psi = -6 constants)
  {
    int t = 1;
    float sD  = (float)((double)t * TWO_KAPPA / 65536.0);
    float tCL = (float)((double)t * CLCONST);
    float s2k = (float)((double)t * TWO_KAPPA);
    iter_kernel<0><<<256, 1024, 0, stream>>>(D16, phib[1], phib[0], psi, partial,
                                             maxd, psimaxU, phimaxU, t, sD, tCL, s2k);
  }
  for (int t = 2; t <= N_ITER; ++t) {
    float prevCL  = (float)((double)(t - 1) * CLCONST);
    float prev2k  = (float)((double)(t - 1) * TWO_KAPPA);
    if (t == 2)
      finish_kernel<1><<<32, 1024, 0, stream>>>(partial, psi, psi, ct, maxd,
                                                psimaxU, phimaxU, t, prevCL, prev2k);
    else
      finish_kernel<0><<<32, 1024, 0, stream>>>(partial, psi, psi, ct, maxd,
                                                psimaxU, phimaxU, t, prevCL, prev2k);
    float sD  = (float)((double)t * TWO_KAPPA / 65536.0);
    float tCL = (float)((double)t * CLCONST);
    float s2k = (float)((double)t * TWO_KAPPA);
    iter_kernel<1><<<256, 1024, 0, stream>>>(D16, phib[t & 1], phib[(t + 1) & 1], psi,
                                             partial, maxd, psimaxU, phimaxU,
                                             t, sD, tCL, s2k);
  }
  // final reduce of iter-30 partials -> ct30 ; psi buffer must keep psi_30,
  // so the psi_31 write goes to a dummy buffer.
  {
    float prevCL = (float)((double)N_ITER * CLCONST);
    float prev2k = (float)((double)N_ITER * TWO_KAPPA);
    finish_kernel<0><<<32, 1024, 0, stream>>>(partial, psi, psidmy, ct, maxd,
                                              psimaxU, phimaxU, N_ITER + 1, prevCL, prev2k);
    loss_kernel<<<1, 1024, 0, stream>>>(ct, psi, colM, maxd, phimaxU, out, prevCL, prev2k);
  }
}